// Round 1
// baseline (883.552 us; speedup 1.0000x reference)
//
#include <hip/hip_runtime.h>

// Problem constants (validated against in_sizes at launch)
#define IN_CH 128
#define HID   64
#define NC    10

__device__ __forceinline__ int lower_bound_i(const int* a, int n, int v) {
    int lo = 0, hi = n;
    while (lo < hi) { int mid = (lo + hi) >> 1; if (a[mid] < v) lo = mid + 1; else hi = mid; }
    return lo;
}

// ---- CSR build ----------------------------------------------------------

__global__ void k_count(const int* __restrict__ dst, int* __restrict__ cnt, int E) {
    int e = blockIdx.x * blockDim.x + threadIdx.x;
    if (e < E) atomicAdd(&cnt[dst[e]], 1);
}

__global__ void k_scan1(const int* __restrict__ cnt, int* __restrict__ excl,
                        int* __restrict__ bsum, int n) {
    __shared__ int s[256];
    int i = blockIdx.x * 256 + threadIdx.x;
    int v = (i < n) ? cnt[i] : 0;
    s[threadIdx.x] = v;
    __syncthreads();
    for (int off = 1; off < 256; off <<= 1) {
        int t = (threadIdx.x >= off) ? s[threadIdx.x - off] : 0;
        __syncthreads();
        s[threadIdx.x] += t;
        __syncthreads();
    }
    if (i < n) excl[i] = s[threadIdx.x] - v;
    if (threadIdx.x == 255) bsum[blockIdx.x] = s[255];
}

__global__ void k_scan2(int* __restrict__ bsum, int nb) {
    __shared__ int s[512];
    int v = (threadIdx.x < nb) ? bsum[threadIdx.x] : 0;
    s[threadIdx.x] = v;
    __syncthreads();
    for (int off = 1; off < 512; off <<= 1) {
        int t = (threadIdx.x >= off) ? s[threadIdx.x - off] : 0;
        __syncthreads();
        s[threadIdx.x] += t;
        __syncthreads();
    }
    if (threadIdx.x < nb) bsum[threadIdx.x] = s[threadIdx.x] - v;  // exclusive, in place
}

__global__ void k_scan3(int* __restrict__ rowptr, const int* __restrict__ bsum,
                        int* __restrict__ cursor, int n, int E) {
    int i = blockIdx.x * 256 + threadIdx.x;
    if (i < n) {
        int r = rowptr[i] + bsum[i >> 8];
        rowptr[i] = r;
        cursor[i] = r;
    }
    if (i == 0) rowptr[n] = E;
}

__global__ void k_dinv(const int* __restrict__ cnt, float* __restrict__ dinv, int n) {
    int i = blockIdx.x * blockDim.x + threadIdx.x;
    if (i < n) dinv[i] = rsqrtf((float)(cnt[i] + 1));  // +1 = self loop; deg>=1 always
}

__global__ void k_fill(const int* __restrict__ src, const int* __restrict__ dst,
                       const float* __restrict__ dinv, int* __restrict__ cursor,
                       int2* __restrict__ meta, int E) {
    int e = blockIdx.x * blockDim.x + threadIdx.x;
    if (e < E) {
        int s = src[e], d = dst[e];
        int pos = atomicAdd(&cursor[d], 1);
        float w = dinv[s] * dinv[d];
        meta[pos] = make_int2(s, __float_as_int(w));
    }
}

// ---- Dense X@W (fp32 vector ALU; no fp32 MFMA on CDNA4) ----------------
// 32 rows/block, 256 threads: col = tid&63, row-group = tid>>6 handles 8 rows.

template <int K>
__global__ void k_gemm(const float* __restrict__ X, const float* __restrict__ W,
                       float* __restrict__ H, int n) {
    __shared__ float xs[32 * K];
    __shared__ float ws[K * 64];
    int tid  = threadIdx.x;
    int row0 = blockIdx.x * 32;
    for (int i = tid * 4; i < K * 64; i += 256 * 4)
        *(float4*)&ws[i] = *(const float4*)&W[i];
    // X tile rows are contiguous in memory: [row0*K, (row0+32)*K)
    for (int i = tid * 4; i < 32 * K; i += 256 * 4) {
        int r = i / K;
        if (row0 + r < n) *(float4*)&xs[i] = *(const float4*)&X[(size_t)row0 * K + i];
        else { xs[i] = 0.f; xs[i+1] = 0.f; xs[i+2] = 0.f; xs[i+3] = 0.f; }
    }
    __syncthreads();
    int col = tid & 63, rg = tid >> 6;
    float acc[8] = {0.f,0.f,0.f,0.f,0.f,0.f,0.f,0.f};
    for (int k = 0; k < K; k++) {
        float wv = ws[k * 64 + col];
#pragma unroll
        for (int r = 0; r < 8; r++) acc[r] += xs[(rg * 8 + r) * K + k] * wv;
    }
#pragma unroll
    for (int r = 0; r < 8; r++) {
        int row = row0 + rg * 8 + r;
        if (row < n) H[(size_t)row * 64 + col] = acc[r];
    }
}

// ---- Normalized scatter-add as CSR gather: one wave per node, lane=col --

__global__ void k_agg(const float* __restrict__ H, const int2* __restrict__ meta,
                      const int* __restrict__ rowptr, const float* __restrict__ dinv,
                      const float* __restrict__ bias, float* __restrict__ out,
                      int n, int do_relu) {
    int wid  = (blockIdx.x * blockDim.x + threadIdx.x) >> 6;  // node
    int lane = threadIdx.x & 63;                              // column
    if (wid >= n) return;
    int beg = rowptr[wid], end = rowptr[wid + 1];
    float dv  = dinv[wid];
    float acc = dv * dv * H[(size_t)wid * 64 + lane];  // self-loop term
    for (int e = beg; e < end; e++) {
        int2 m = meta[e];
        acc += __int_as_float(m.y) * H[(size_t)m.x * 64 + lane];
    }
    if (bias) acc += bias[lane];
    if (do_relu) acc = fmaxf(acc, 0.f);
    out[(size_t)wid * 64 + lane] = acc;
}

// ---- Mean pool per graph (batch sorted -> binary-search boundaries) -----

__global__ void k_pool(const float* __restrict__ G, const int* __restrict__ batch,
                       float* __restrict__ P, int n) {
    int g  = blockIdx.x;
    int lo = lower_bound_i(batch, n, g);
    int hi = lower_bound_i(batch, n, g + 1);
    int col = threadIdx.x & 63, rg = threadIdx.x >> 6;
    float acc = 0.f;
    for (int r = lo + rg; r < hi; r += 4) acc += G[(size_t)r * 64 + col];
    __shared__ float s[4][64];
    s[rg][col] = acc;
    __syncthreads();
    if (rg == 0) {
        float v = s[0][col] + s[1][col] + s[2][col] + s[3][col];
        int c = hi - lo;
        P[g * 64 + col] = v / (float)max(c, 1);
    }
}

// ---- pooled @ W3 + b3, then log_softmax (64 graphs x 10 classes) --------

__global__ void k_final(const float* __restrict__ P, const float* __restrict__ W3,
                        const float* __restrict__ b3, float* __restrict__ out, int ng) {
    __shared__ float s[64][NC];
    __shared__ float lse[64];
    int t = threadIdx.x;
    if (t < ng * NC) {
        int g = t / NC, c = t % NC;
        float acc = b3[c];
        for (int k = 0; k < 64; k++) acc += P[g * 64 + k] * W3[k * NC + c];
        s[g][c] = acc;
    }
    __syncthreads();
    if (t < ng) {
        float m = -1e30f;
        for (int c = 0; c < NC; c++) m = fmaxf(m, s[t][c]);
        float sum = 0.f;
        for (int c = 0; c < NC; c++) sum += expf(s[t][c] - m);
        lse[t] = m + logf(sum);
    }
    __syncthreads();
    if (t < ng * NC) {
        int g = t / NC, c = t % NC;
        out[t] = s[g][c] - lse[g];
    }
}

// ---- launch -------------------------------------------------------------

extern "C" void kernel_launch(void* const* d_in, const int* in_sizes, int n_in,
                              void* d_out, int out_size, void* d_ws, size_t ws_size,
                              hipStream_t stream) {
    const float* x     = (const float*)d_in[0];
    const int*   ei    = (const int*)  d_in[1];
    const int*   batch = (const int*)  d_in[2];
    const float* W1    = (const float*)d_in[3];
    const float* b1    = (const float*)d_in[4];
    const float* W2    = (const float*)d_in[5];
    const float* b2    = (const float*)d_in[6];
    const float* W3    = (const float*)d_in[7];
    const float* b3    = (const float*)d_in[8];
    float*       out   = (float*)d_out;

    const int NN = in_sizes[0] / IN_CH;   // 100000
    const int E  = in_sizes[1] / 2;       // 1600000
    const int NG = out_size / NC;         // 64

    const int* src = ei;
    const int* dst = ei + E;

    // workspace carve-up (256B aligned); total ~67 MB
    char* ws = (char*)d_ws;
    size_t off = 0;
    auto carve = [&](size_t bytes) -> char* {
        char* p = ws + off;
        off = (off + bytes + 255) & ~(size_t)255;
        return p;
    };
    int*   cnt    = (int*)  carve((size_t)NN * 4);
    int*   rowptr = (int*)  carve((size_t)(NN + 1) * 4);
    int*   cursor = (int*)  carve((size_t)NN * 4);
    float* dinv   = (float*)carve((size_t)NN * 4);
    int*   bsum   = (int*)  carve(4096);
    int2*  meta   = (int2*) carve((size_t)E * 8);
    float* bufA   = (float*)carve((size_t)NN * HID * 4);
    float* bufB   = (float*)carve((size_t)NN * HID * 4);
    float* P      = (float*)carve((size_t)NG * HID * 4);
    (void)ws_size;

    const int nbN = (NN + 255) / 256;   // 391
    const int nbE = (E + 255) / 256;    // 6250

    hipMemsetAsync(cnt, 0, (size_t)NN * 4, stream);
    k_count<<<nbE, 256, 0, stream>>>(dst, cnt, E);
    k_scan1<<<nbN, 256, 0, stream>>>(cnt, rowptr, bsum, NN);
    k_scan2<<<1, 512, 0, stream>>>(bsum, nbN);
    k_scan3<<<nbN, 256, 0, stream>>>(rowptr, bsum, cursor, NN, E);
    k_dinv <<<nbN, 256, 0, stream>>>(cnt, dinv, NN);
    k_fill <<<nbE, 256, 0, stream>>>(src, dst, dinv, cursor, meta, E);

    const int nbG = (NN + 31) / 32;               // GEMM blocks (32 rows each)
    const int nbA = ((size_t)NN * 64 + 255) / 256; // agg blocks (4 waves each)

    // layer 1: h1 = relu(A(xW1) + b1)
    k_gemm<IN_CH><<<nbG, 256, 0, stream>>>(x, W1, bufA, NN);
    k_agg<<<nbA, 256, 0, stream>>>(bufA, meta, rowptr, dinv, b1, bufB, NN, 1);
    // layer 2: h2 = relu(A(h1W2) + b2)
    k_gemm<HID><<<nbG, 256, 0, stream>>>(bufB, W2, bufA, NN);
    k_agg<<<nbA, 256, 0, stream>>>(bufA, meta, rowptr, dinv, b2, bufB, NN, 1);
    // layer 3 reordered: g = A h2 ; pooled = mean(g) ; out = pooled@W3 + b3
    k_agg<<<nbA, 256, 0, stream>>>(bufB, meta, rowptr, dinv, nullptr, bufA, NN, 0);
    k_pool<<<NG, 256, 0, stream>>>(bufA, batch, P, NN);
    k_final<<<1, NG * NC, 0, stream>>>(P, W3, b3, out, NG);
}

// Round 2
// 801.083 us; speedup vs baseline: 1.1029x; 1.1029x over previous
//
#include <hip/hip_runtime.h>

#define IN_CH 128
#define HID   64
#define NC    10

__device__ __forceinline__ int lower_bound_i(const int* a, int n, int v) {
    int lo = 0, hi = n;
    while (lo < hi) { int mid = (lo + hi) >> 1; if (a[mid] < v) lo = mid + 1; else hi = mid; }
    return lo;
}

// ---- CSR build ----------------------------------------------------------

__global__ void k_count(const int* __restrict__ dst, int* __restrict__ cnt, int E) {
    int e = blockIdx.x * blockDim.x + threadIdx.x;
    if (e < E) atomicAdd(&cnt[dst[e]], 1);
}

__global__ void k_scan1(const int* __restrict__ cnt, int* __restrict__ excl,
                        int* __restrict__ bsum, int n) {
    __shared__ int s[256];
    int i = blockIdx.x * 256 + threadIdx.x;
    int v = (i < n) ? cnt[i] : 0;
    s[threadIdx.x] = v;
    __syncthreads();
    for (int off = 1; off < 256; off <<= 1) {
        int t = (threadIdx.x >= off) ? s[threadIdx.x - off] : 0;
        __syncthreads();
        s[threadIdx.x] += t;
        __syncthreads();
    }
    if (i < n) excl[i] = s[threadIdx.x] - v;
    if (threadIdx.x == 255) bsum[blockIdx.x] = s[255];
}

__global__ void k_scan2(int* __restrict__ bsum, int nb) {
    __shared__ int s[512];
    int v = (threadIdx.x < nb) ? bsum[threadIdx.x] : 0;
    s[threadIdx.x] = v;
    __syncthreads();
    for (int off = 1; off < 512; off <<= 1) {
        int t = (threadIdx.x >= off) ? s[threadIdx.x - off] : 0;
        __syncthreads();
        s[threadIdx.x] += t;
        __syncthreads();
    }
    if (threadIdx.x < nb) bsum[threadIdx.x] = s[threadIdx.x] - v;  // exclusive, in place
}

__global__ void k_scan3(int* __restrict__ rowptr, const int* __restrict__ bsum,
                        int* __restrict__ cursor, int n, int E) {
    int i = blockIdx.x * 256 + threadIdx.x;
    if (i < n) {
        int r = rowptr[i] + bsum[i >> 8];
        rowptr[i] = r;
        cursor[i] = r;
    }
    if (i == 0) rowptr[n] = E;
}

__global__ void k_dinv(const int* __restrict__ cnt, float* __restrict__ dinv, int n) {
    int i = blockIdx.x * blockDim.x + threadIdx.x;
    if (i < n) dinv[i] = rsqrtf((float)(cnt[i] + 1));  // +1 self loop
}

__global__ void k_fill(const int* __restrict__ src, const int* __restrict__ dst,
                       const float* __restrict__ dinv, int* __restrict__ cursor,
                       int2* __restrict__ meta, int E) {
    int e = blockIdx.x * blockDim.x + threadIdx.x;
    if (e < E) {
        int s = src[e], d = dst[e];
        int pos = atomicAdd(&cursor[d], 1);
        float w = dinv[s] * dinv[d];
        meta[pos] = make_int2(s, __float_as_int(w));
    }
}

// ---- Dense X@W: 128 rows/block, 8x4 register tile, K-chunks of 32 -------
// thread: cg = tid&15 -> cols cg*4..+3 ; rg = tid>>4 -> rows rg*8..+7
// xs staged as float4 [row][k4] with XOR swizzle k4 ^ ((row>>3)&3):
//   compute-read bank-quad = (k4 ^ rg) mod 8 -> distinct per rg, conflict-free.
// ws [k][cg] float4: read quad = cg mod 8 -> 2-way (free per m136).

template <int K>
__global__ __launch_bounds__(256) void k_gemm(const float* __restrict__ X,
                                              const float* __restrict__ W,
                                              float* __restrict__ H, int n) {
    __shared__ float4 xs4[128][8];
    __shared__ float4 ws4[32][16];
    int tid  = threadIdx.x;
    int row0 = blockIdx.x * 128;
    int cg = tid & 15, rg = tid >> 4;
    float acc[8][4];
#pragma unroll
    for (int r = 0; r < 8; r++)
#pragma unroll
        for (int c = 0; c < 4; c++) acc[r][c] = 0.f;

    for (int k0 = 0; k0 < K; k0 += 32) {
        // stage X chunk (128 rows x 32 floats)
        int sr = tid >> 3, f4 = tid & 7;
#pragma unroll
        for (int i = 0; i < 4; i++) {
            int row  = sr + i * 32;
            int grow = row0 + row;
            float4 v = make_float4(0.f, 0.f, 0.f, 0.f);
            if (grow < n) v = *(const float4*)&X[(size_t)grow * K + k0 + f4 * 4];
            xs4[row][f4 ^ ((row >> 3) & 3)] = v;
        }
        // stage W chunk (32 x 64 floats = 512 float4)
        {
            const float4* Wp = (const float4*)&W[(size_t)k0 * 64];
            int j0 = tid, j1 = tid + 256;
            ws4[j0 >> 4][j0 & 15] = Wp[j0];
            ws4[j1 >> 4][j1 & 15] = Wp[j1];
        }
        __syncthreads();
#pragma unroll
        for (int k4 = 0; k4 < 8; k4++) {
            float4 av[8];
#pragma unroll
            for (int r = 0; r < 8; r++) av[r] = xs4[rg * 8 + r][k4 ^ (rg & 3)];
            float4 wv[4];
#pragma unroll
            for (int kk = 0; kk < 4; kk++) wv[kk] = ws4[k4 * 4 + kk][cg];
#pragma unroll
            for (int kk = 0; kk < 4; kk++) {
#pragma unroll
                for (int r = 0; r < 8; r++) {
                    float a = ((const float*)&av[r])[kk];
                    acc[r][0] += a * wv[kk].x;
                    acc[r][1] += a * wv[kk].y;
                    acc[r][2] += a * wv[kk].z;
                    acc[r][3] += a * wv[kk].w;
                }
            }
        }
        __syncthreads();
    }
#pragma unroll
    for (int r = 0; r < 8; r++) {
        int row = row0 + rg * 8 + r;
        if (row < n)
            *(float4*)&H[(size_t)row * 64 + cg * 4] =
                make_float4(acc[r][0], acc[r][1], acc[r][2], acc[r][3]);
    }
}

// ---- CSR gather agg: wave/node, lane=col, 8-slot predicated unroll ------

__global__ void k_agg(const float* __restrict__ H, const int2* __restrict__ meta,
                      const int* __restrict__ rowptr, const float* __restrict__ dinv,
                      const float* __restrict__ bias, float* __restrict__ out,
                      int n, int do_relu) {
    int wid  = (blockIdx.x * blockDim.x + threadIdx.x) >> 6;
    int lane = threadIdx.x & 63;
    if (wid >= n) return;
    int beg = rowptr[wid], end = rowptr[wid + 1];
    float dv = dinv[wid];
    float a[8];
    a[0] = dv * dv * H[(size_t)wid * 64 + lane];  // self loop
#pragma unroll
    for (int j = 1; j < 8; j++) a[j] = 0.f;
    for (int e = beg; e < end; e += 8) {
#pragma unroll
        for (int j = 0; j < 8; j++) {
            int ej = e + j;
            if (ej < end) {
                int2 m = meta[ej];
                a[j] += __int_as_float(m.y) * H[(size_t)m.x * 64 + lane];
            }
        }
    }
    float acc = ((a[0] + a[1]) + (a[2] + a[3])) + ((a[4] + a[5]) + (a[6] + a[7]));
    if (bias) acc += bias[lane];
    if (do_relu) acc = fmaxf(acc, 0.f);
    out[(size_t)wid * 64 + lane] = acc;
}

// ---- Mean pool, chunk-parallel: 256 rows/block, segment-flush atomics ---

__global__ void k_pool(const float* __restrict__ G, const int* __restrict__ batch,
                       float* __restrict__ Psum, int n) {
    int base = blockIdx.x * 256;
    int lane = threadIdx.x & 63, rg = threadIdx.x >> 6;
    int lim = min(base + 256, n);
    int cur = -1;
    float acc = 0.f;
    for (int r = base + rg; r < lim; r += 4) {
        int g = batch[r];
        if (g != cur) {
            if (cur >= 0) atomicAdd(&Psum[cur * 64 + lane], acc);
            cur = g;
            acc = 0.f;
        }
        acc += G[(size_t)r * 64 + lane];
    }
    if (cur >= 0) atomicAdd(&Psum[cur * 64 + lane], acc);
}

// ---- mean + pooled@W3 + b3 + log_softmax (one block, 640 threads) -------

__global__ void k_final(const float* __restrict__ Psum, const int* __restrict__ batch,
                        int n, const float* __restrict__ W3, const float* __restrict__ b3,
                        float* __restrict__ out, int ng) {
    __shared__ float P[64 * 64];
    __shared__ float s[64][NC];
    __shared__ float lse[64];
    __shared__ float invc[64];
    int t = threadIdx.x;
    if (t < ng) {
        int lo = lower_bound_i(batch, n, t);
        int hi = lower_bound_i(batch, n, t + 1);
        invc[t] = 1.f / (float)max(hi - lo, 1);
    }
    __syncthreads();
    for (int i = t; i < ng * 64; i += blockDim.x) P[i] = Psum[i] * invc[i >> 6];
    __syncthreads();
    if (t < ng * NC) {
        int g = t / NC, c = t % NC;
        float acc = b3[c];
        for (int k = 0; k < 64; k++) acc += P[g * 64 + k] * W3[k * NC + c];
        s[g][c] = acc;
    }
    __syncthreads();
    if (t < ng) {
        float m = -1e30f;
        for (int c = 0; c < NC; c++) m = fmaxf(m, s[t][c]);
        float sum = 0.f;
        for (int c = 0; c < NC; c++) sum += expf(s[t][c] - m);
        lse[t] = m + logf(sum);
    }
    __syncthreads();
    if (t < ng * NC) {
        int g = t / NC, c = t % NC;
        out[t] = s[g][c] - lse[g];
    }
}

// ---- launch -------------------------------------------------------------

extern "C" void kernel_launch(void* const* d_in, const int* in_sizes, int n_in,
                              void* d_out, int out_size, void* d_ws, size_t ws_size,
                              hipStream_t stream) {
    const float* x     = (const float*)d_in[0];
    const int*   ei    = (const int*)  d_in[1];
    const int*   batch = (const int*)  d_in[2];
    const float* W1    = (const float*)d_in[3];
    const float* b1    = (const float*)d_in[4];
    const float* W2    = (const float*)d_in[5];
    const float* b2    = (const float*)d_in[6];
    const float* W3    = (const float*)d_in[7];
    const float* b3    = (const float*)d_in[8];
    float*       out   = (float*)d_out;

    const int NN = in_sizes[0] / IN_CH;   // 100000
    const int E  = in_sizes[1] / 2;       // 1600000
    const int NG = out_size / NC;         // 64

    const int* src = ei;
    const int* dst = ei + E;

    char* ws = (char*)d_ws;
    size_t off = 0;
    auto carve = [&](size_t bytes) -> char* {
        char* p = ws + off;
        off = (off + bytes + 255) & ~(size_t)255;
        return p;
    };
    int*   cnt    = (int*)  carve((size_t)NN * 4);
    int*   rowptr = (int*)  carve((size_t)(NN + 1) * 4);
    int*   cursor = (int*)  carve((size_t)NN * 4);
    float* dinv   = (float*)carve((size_t)NN * 4);
    int*   bsum   = (int*)  carve(4096);
    int2*  meta   = (int2*) carve((size_t)E * 8);
    float* bufA   = (float*)carve((size_t)NN * HID * 4);
    float* bufB   = (float*)carve((size_t)NN * HID * 4);
    float* Psum   = (float*)carve((size_t)NG * HID * 4);
    (void)ws_size;

    const int nbN = (NN + 255) / 256;   // 391
    const int nbE = (E + 255) / 256;    // 6250

    hipMemsetAsync(cnt, 0, (size_t)NN * 4, stream);
    hipMemsetAsync(Psum, 0, (size_t)NG * HID * 4, stream);
    k_count<<<nbE, 256, 0, stream>>>(dst, cnt, E);
    k_scan1<<<nbN, 256, 0, stream>>>(cnt, rowptr, bsum, NN);
    k_scan2<<<1, 512, 0, stream>>>(bsum, nbN);
    k_scan3<<<nbN, 256, 0, stream>>>(rowptr, bsum, cursor, NN, E);
    k_dinv <<<nbN, 256, 0, stream>>>(cnt, dinv, NN);
    k_fill <<<nbE, 256, 0, stream>>>(src, dst, dinv, cursor, meta, E);

    const int nbG = (NN + 127) / 128;               // 782
    const int nbA = ((size_t)NN * 64 + 255) / 256;  // 25000

    k_gemm<IN_CH><<<nbG, 256, 0, stream>>>(x, W1, bufA, NN);
    k_agg<<<nbA, 256, 0, stream>>>(bufA, meta, rowptr, dinv, b1, bufB, NN, 1);
    k_gemm<HID><<<nbG, 256, 0, stream>>>(bufB, W2, bufA, NN);
    k_agg<<<nbA, 256, 0, stream>>>(bufA, meta, rowptr, dinv, b2, bufB, NN, 1);
    k_agg<<<nbA, 256, 0, stream>>>(bufB, meta, rowptr, dinv, nullptr, bufA, NN, 0);
    k_pool<<<nbN, 256, 0, stream>>>(bufA, batch, Psum, NN);
    k_final<<<1, 640, 0, stream>>>(Psum, batch, NN, W3, b3, out, NG);
}

// Round 3
// 588.746 us; speedup vs baseline: 1.5007x; 1.3607x over previous
//
#include <hip/hip_runtime.h>

#define IN_CH 128
#define HID   64
#define NC    10

__device__ __forceinline__ int lower_bound_i(const int* a, int n, int v) {
    int lo = 0, hi = n;
    while (lo < hi) { int mid = (lo + hi) >> 1; if (a[mid] < v) lo = mid + 1; else hi = mid; }
    return lo;
}

// ---- CSR build ----------------------------------------------------------

__global__ void k_count(const int* __restrict__ dst, int* __restrict__ cnt, int E) {
    int e = blockIdx.x * blockDim.x + threadIdx.x;
    if (e < E) atomicAdd(&cnt[dst[e]], 1);
}

__global__ void k_scan1(const int* __restrict__ cnt, int* __restrict__ excl,
                        int* __restrict__ bsum, int n) {
    __shared__ int s[256];
    int i = blockIdx.x * 256 + threadIdx.x;
    int v = (i < n) ? cnt[i] : 0;
    s[threadIdx.x] = v;
    __syncthreads();
    for (int off = 1; off < 256; off <<= 1) {
        int t = (threadIdx.x >= off) ? s[threadIdx.x - off] : 0;
        __syncthreads();
        s[threadIdx.x] += t;
        __syncthreads();
    }
    if (i < n) excl[i] = s[threadIdx.x] - v;
    if (threadIdx.x == 255) bsum[blockIdx.x] = s[255];
}

__global__ void k_scan2(int* __restrict__ bsum, int nb) {
    __shared__ int s[512];
    int v = (threadIdx.x < nb) ? bsum[threadIdx.x] : 0;
    s[threadIdx.x] = v;
    __syncthreads();
    for (int off = 1; off < 512; off <<= 1) {
        int t = (threadIdx.x >= off) ? s[threadIdx.x - off] : 0;
        __syncthreads();
        s[threadIdx.x] += t;
        __syncthreads();
    }
    if (threadIdx.x < nb) bsum[threadIdx.x] = s[threadIdx.x] - v;  // exclusive, in place
}

__global__ void k_scan3(int* __restrict__ rowptr, const int* __restrict__ bsum,
                        int* __restrict__ cursor, int n, int E) {
    int i = blockIdx.x * 256 + threadIdx.x;
    if (i < n) {
        int r = rowptr[i] + bsum[i >> 8];
        rowptr[i] = r;
        cursor[i] = r;
    }
    if (i == 0) rowptr[n] = E;
}

__global__ void k_dinv(const int* __restrict__ cnt, float* __restrict__ dinv, int n) {
    int i = blockIdx.x * blockDim.x + threadIdx.x;
    if (i < n) dinv[i] = rsqrtf((float)(cnt[i] + 1));  // +1 self loop
}

__global__ void k_fill(const int* __restrict__ src, const int* __restrict__ dst,
                       const float* __restrict__ dinv, int* __restrict__ cursor,
                       int2* __restrict__ meta, int E) {
    int e = blockIdx.x * blockDim.x + threadIdx.x;
    if (e < E) {
        int s = src[e], d = dst[e];
        int pos = atomicAdd(&cursor[d], 1);
        float w = dinv[s] * dinv[d];
        meta[pos] = make_int2(s, __float_as_int(w));
    }
}

// ---- Dense X@W: 128 rows/block, 8x4 register tile, K-chunks of 32 -------

template <int K>
__global__ __launch_bounds__(256) void k_gemm(const float* __restrict__ X,
                                              const float* __restrict__ W,
                                              float* __restrict__ H, int n) {
    __shared__ float4 xs4[128][8];
    __shared__ float4 ws4[32][16];
    int tid  = threadIdx.x;
    int row0 = blockIdx.x * 128;
    int cg = tid & 15, rg = tid >> 4;
    float acc[8][4];
#pragma unroll
    for (int r = 0; r < 8; r++)
#pragma unroll
        for (int c = 0; c < 4; c++) acc[r][c] = 0.f;

    for (int k0 = 0; k0 < K; k0 += 32) {
        int sr = tid >> 3, f4 = tid & 7;
#pragma unroll
        for (int i = 0; i < 4; i++) {
            int row  = sr + i * 32;
            int grow = row0 + row;
            float4 v = make_float4(0.f, 0.f, 0.f, 0.f);
            if (grow < n) v = *(const float4*)&X[(size_t)grow * K + k0 + f4 * 4];
            xs4[row][f4 ^ ((row >> 3) & 3)] = v;
        }
        {
            const float4* Wp = (const float4*)&W[(size_t)k0 * 64];
            int j0 = tid, j1 = tid + 256;
            ws4[j0 >> 4][j0 & 15] = Wp[j0];
            ws4[j1 >> 4][j1 & 15] = Wp[j1];
        }
        __syncthreads();
#pragma unroll
        for (int k4 = 0; k4 < 8; k4++) {
            float4 av[8];
#pragma unroll
            for (int r = 0; r < 8; r++) av[r] = xs4[rg * 8 + r][k4 ^ (rg & 3)];
            float4 wv[4];
#pragma unroll
            for (int kk = 0; kk < 4; kk++) wv[kk] = ws4[k4 * 4 + kk][cg];
#pragma unroll
            for (int kk = 0; kk < 4; kk++) {
#pragma unroll
                for (int r = 0; r < 8; r++) {
                    float a = ((const float*)&av[r])[kk];
                    acc[r][0] += a * wv[kk].x;
                    acc[r][1] += a * wv[kk].y;
                    acc[r][2] += a * wv[kk].z;
                    acc[r][3] += a * wv[kk].w;
                }
            }
        }
        __syncthreads();
    }
#pragma unroll
    for (int r = 0; r < 8; r++) {
        int row = row0 + rg * 8 + r;
        if (row < n)
            *(float4*)&H[(size_t)row * 64 + cg * 4] =
                make_float4(acc[r][0], acc[r][1], acc[r][2], acc[r][3]);
    }
}

// ---- CSR gather agg: wave/node, lane=col, BRANCHLESS 8-deep MLP ---------
// Tail edges are index-clamped to beg (always valid once loop entered) and
// weight-zeroed via cndmask -> no branches inside the group, so all 8 meta
// loads then all 8 H gathers issue before any waitcnt drain.

__global__ void k_agg(const float* __restrict__ H, const int2* __restrict__ meta,
                      const int* __restrict__ rowptr, const float* __restrict__ dinv,
                      const float* __restrict__ bias, float* __restrict__ out,
                      int n, int do_relu) {
    int wid  = (blockIdx.x * blockDim.x + threadIdx.x) >> 6;
    int lane = threadIdx.x & 63;
    if (wid >= n) return;
    int beg = rowptr[wid], end = rowptr[wid + 1];
    float dv = dinv[wid];
    float a[8];
    a[0] = dv * dv * H[(size_t)wid * 64 + lane];  // self loop
#pragma unroll
    for (int j = 1; j < 8; j++) a[j] = 0.f;
    for (int e = beg; e < end; e += 8) {
        int2 m[8];
#pragma unroll
        for (int j = 0; j < 8; j++) {
            int ej  = e + j;
            int idx = (ej < end) ? ej : beg;   // branchless clamp
            m[j] = meta[idx];
        }
#pragma unroll
        for (int j = 0; j < 8; j++) {
            float wj = (e + j < end) ? __int_as_float(m[j].y) : 0.f;
            a[j] += wj * H[(size_t)m[j].x * 64 + lane];
        }
    }
    float acc = ((a[0] + a[1]) + (a[2] + a[3])) + ((a[4] + a[5]) + (a[6] + a[7]));
    if (bias) acc += bias[lane];
    if (do_relu) acc = fmaxf(acc, 0.f);
    out[(size_t)wid * 64 + lane] = acc;
}

// ---- Mean pool, chunk-parallel: 256 rows/block, segment-flush atomics ---

__global__ void k_pool(const float* __restrict__ G, const int* __restrict__ batch,
                       float* __restrict__ Psum, int n) {
    int base = blockIdx.x * 256;
    int lane = threadIdx.x & 63, rg = threadIdx.x >> 6;
    int lim = min(base + 256, n);
    int cur = -1;
    float acc = 0.f;
    for (int r = base + rg; r < lim; r += 4) {
        int g = batch[r];
        if (g != cur) {
            if (cur >= 0) atomicAdd(&Psum[cur * 64 + lane], acc);
            cur = g;
            acc = 0.f;
        }
        acc += G[(size_t)r * 64 + lane];
    }
    if (cur >= 0) atomicAdd(&Psum[cur * 64 + lane], acc);
}

// ---- mean + pooled@W3 + b3 + log_softmax (one block, 640 threads) -------

__global__ void k_final(const float* __restrict__ Psum, const int* __restrict__ batch,
                        int n, const float* __restrict__ W3, const float* __restrict__ b3,
                        float* __restrict__ out, int ng) {
    __shared__ float P[64 * 64];
    __shared__ float s[64][NC];
    __shared__ float lse[64];
    __shared__ float invc[64];
    int t = threadIdx.x;
    if (t < ng) {
        int lo = lower_bound_i(batch, n, t);
        int hi = lower_bound_i(batch, n, t + 1);
        invc[t] = 1.f / (float)max(hi - lo, 1);
    }
    __syncthreads();
    for (int i = t; i < ng * 64; i += blockDim.x) P[i] = Psum[i] * invc[i >> 6];
    __syncthreads();
    if (t < ng * NC) {
        int g = t / NC, c = t % NC;
        float acc = b3[c];
        for (int k = 0; k < 64; k++) acc += P[g * 64 + k] * W3[k * NC + c];
        s[g][c] = acc;
    }
    __syncthreads();
    if (t < ng) {
        float m = -1e30f;
        for (int c = 0; c < NC; c++) m = fmaxf(m, s[t][c]);
        float sum = 0.f;
        for (int c = 0; c < NC; c++) sum += expf(s[t][c] - m);
        lse[t] = m + logf(sum);
    }
    __syncthreads();
    if (t < ng * NC) {
        int g = t / NC, c = t % NC;
        out[t] = s[g][c] - lse[g];
    }
}

// ---- launch -------------------------------------------------------------

extern "C" void kernel_launch(void* const* d_in, const int* in_sizes, int n_in,
                              void* d_out, int out_size, void* d_ws, size_t ws_size,
                              hipStream_t stream) {
    const float* x     = (const float*)d_in[0];
    const int*   ei    = (const int*)  d_in[1];
    const int*   batch = (const int*)  d_in[2];
    const float* W1    = (const float*)d_in[3];
    const float* b1    = (const float*)d_in[4];
    const float* W2    = (const float*)d_in[5];
    const float* b2    = (const float*)d_in[6];
    const float* W3    = (const float*)d_in[7];
    const float* b3    = (const float*)d_in[8];
    float*       out   = (float*)d_out;

    const int NN = in_sizes[0] / IN_CH;   // 100000
    const int E  = in_sizes[1] / 2;       // 1600000
    const int NG = out_size / NC;         // 64

    const int* src = ei;
    const int* dst = ei + E;

    char* ws = (char*)d_ws;
    size_t off = 0;
    auto carve = [&](size_t bytes) -> char* {
        char* p = ws + off;
        off = (off + bytes + 255) & ~(size_t)255;
        return p;
    };
    int*   cnt    = (int*)  carve((size_t)NN * 4);
    int*   rowptr = (int*)  carve((size_t)(NN + 1) * 4);
    int*   cursor = (int*)  carve((size_t)NN * 4);
    float* dinv   = (float*)carve((size_t)NN * 4);
    int*   bsum   = (int*)  carve(4096);
    int2*  meta   = (int2*) carve((size_t)E * 8);
    float* bufA   = (float*)carve((size_t)NN * HID * 4);
    float* bufB   = (float*)carve((size_t)NN * HID * 4);
    float* Psum   = (float*)carve((size_t)NG * HID * 4);
    (void)ws_size;

    const int nbN = (NN + 255) / 256;   // 391
    const int nbE = (E + 255) / 256;    // 6250

    hipMemsetAsync(cnt, 0, (size_t)NN * 4, stream);
    hipMemsetAsync(Psum, 0, (size_t)NG * HID * 4, stream);
    k_count<<<nbE, 256, 0, stream>>>(dst, cnt, E);
    k_scan1<<<nbN, 256, 0, stream>>>(cnt, rowptr, bsum, NN);
    k_scan2<<<1, 512, 0, stream>>>(bsum, nbN);
    k_scan3<<<nbN, 256, 0, stream>>>(rowptr, bsum, cursor, NN, E);
    k_dinv <<<nbN, 256, 0, stream>>>(cnt, dinv, NN);
    k_fill <<<nbE, 256, 0, stream>>>(src, dst, dinv, cursor, meta, E);

    const int nbG = (NN + 127) / 128;               // 782
    const int nbA = ((size_t)NN * 64 + 255) / 256;  // 25000

    k_gemm<IN_CH><<<nbG, 256, 0, stream>>>(x, W1, bufA, NN);
    k_agg<<<nbA, 256, 0, stream>>>(bufA, meta, rowptr, dinv, b1, bufB, NN, 1);
    k_gemm<HID><<<nbG, 256, 0, stream>>>(bufB, W2, bufA, NN);
    k_agg<<<nbA, 256, 0, stream>>>(bufA, meta, rowptr, dinv, b2, bufB, NN, 1);
    k_agg<<<nbA, 256, 0, stream>>>(bufB, meta, rowptr, dinv, nullptr, bufA, NN, 0);
    k_pool<<<nbN, 256, 0, stream>>>(bufA, batch, Psum, NN);
    k_final<<<1, 640, 0, stream>>>(Psum, batch, NN, W3, b3, out, NG);
}